// Round 1
// baseline (761.411 us; speedup 1.0000x reference)
//
#include <hip/hip_runtime.h>
#include <math.h>

#define D     512
#define KCB   1024
#define TB    16
#define NT    256
#define ALPHA 10.0f

__device__ __forceinline__ float wave_reduce_sum(float v) {
    #pragma unroll
    for (int off = 32; off >= 1; off >>= 1) v += __shfl_xor(v, off, 64);
    return v;
}

// ---------------- K0: zero the ws accumulators (ws is poisoned 0xAA each call)
__global__ void k_init(float* __restrict__ avg, float* __restrict__ sse, float* __restrict__ clu) {
    int t = threadIdx.x + blockIdx.x * blockDim.x;
    if (t < KCB) avg[t] = 0.0f;
    if (t == 0) { *sse = 0.0f; *clu = 0.0f; }
}

// ---------------- K1: cbT[d][k] = normalize(emb[k])[d]  (transposed for coalesced attention reads)
__global__ __launch_bounds__(NT) void k_cbt(const float* __restrict__ emb, float* __restrict__ cbT) {
    const int k = blockIdx.x;
    const int t = threadIdx.x;
    const int wv = t >> 6, lane = t & 63;
    const float2* e2 = (const float2*)(emb + (size_t)k * D);
    float2 v = e2[t];                      // d = 2t, 2t+1
    float ss = v.x * v.x + v.y * v.y;
    ss = wave_reduce_sum(ss);
    __shared__ float part[4];
    __shared__ float s_inv;
    if (lane == 0) part[wv] = ss;
    __syncthreads();
    if (t == 0) {
        float tot = part[0] + part[1] + part[2] + part[3];
        s_inv = 1.0f / fmaxf(sqrtf(tot), 1e-12f);
    }
    __syncthreads();
    float inv = s_inv;
    cbT[(size_t)(2 * t)     * KCB + k] = v.x * inv;
    cbT[(size_t)(2 * t + 1) * KCB + k] = v.y * inv;
}

// ---------------- K2: ln + attention + softmax + argmax + soft_assign + hard_quantized + partial stats
__global__ __launch_bounds__(NT) void k_attn(
    const float* __restrict__ lat, const float* __restrict__ emb,
    const float* __restrict__ cbT,
    float* __restrict__ inv_ws, float* __restrict__ avg_ws, float* __restrict__ clu_ws,
    float* __restrict__ soft_out, float* __restrict__ argm_out, float* __restrict__ hq_out)
{
    __shared__ float4 ln4[TB][D / 4];       // 32 KB, broadcast-read in the GEMM loop
    __shared__ float  s_maxp[4][TB];
    __shared__ int    s_argp[4][TB];
    __shared__ float  s_sump[4][TB];
    __shared__ float  s_rowmax[TB];
    __shared__ int    s_rowarg[TB];
    __shared__ float  s_rowinv[TB];

    const int t    = threadIdx.x;
    const int wv   = t >> 6, lane = t & 63;
    const int b0   = blockIdx.x * TB;

    // ---- Phase A: normalize 16 latent rows into LDS (wave wv handles rows 4wv..4wv+3)
    #pragma unroll
    for (int i = 0; i < 4; ++i) {
        int r = wv * 4 + i;
        int g = b0 + r;
        const float4* lp = (const float4*)(lat + (size_t)g * D);
        float4 a = lp[lane * 2], b = lp[lane * 2 + 1];
        float ss = a.x*a.x + a.y*a.y + a.z*a.z + a.w*a.w
                 + b.x*b.x + b.y*b.y + b.z*b.z + b.w*b.w;
        ss = wave_reduce_sum(ss);
        float inv = 1.0f / fmaxf(sqrtf(ss), 1e-12f);
        ln4[r][lane * 2]     = make_float4(a.x*inv, a.y*inv, a.z*inv, a.w*inv);
        ln4[r][lane * 2 + 1] = make_float4(b.x*inv, b.y*inv, b.z*inv, b.w*inv);
        if (lane == 0) inv_ws[g] = inv;
    }
    __syncthreads();

    // ---- Phase B: attention tile [16][1024]; thread t owns cols k = 4t..4t+3
    float4 acc[TB];
    #pragma unroll
    for (int r = 0; r < TB; ++r) acc[r] = make_float4(0.f, 0.f, 0.f, 0.f);
    const float4* cb4 = (const float4*)cbT;         // [d][K/4]
    for (int d4 = 0; d4 < D / 4; ++d4) {
        const int d = d4 * 4;
        float4 c0 = cb4[(size_t)(d + 0) * (KCB / 4) + t];
        float4 c1 = cb4[(size_t)(d + 1) * (KCB / 4) + t];
        float4 c2 = cb4[(size_t)(d + 2) * (KCB / 4) + t];
        float4 c3 = cb4[(size_t)(d + 3) * (KCB / 4) + t];
        #pragma unroll
        for (int r = 0; r < TB; ++r) {
            float4 L = ln4[r][d4];
            acc[r].x += L.x*c0.x + L.y*c1.x + L.z*c2.x + L.w*c3.x;
            acc[r].y += L.x*c0.y + L.y*c1.y + L.z*c2.y + L.w*c3.y;
            acc[r].z += L.x*c0.z + L.y*c1.z + L.z*c2.z + L.w*c3.z;
            acc[r].w += L.x*c0.w + L.y*c1.w + L.z*c2.w + L.w*c3.w;
        }
    }

    // ---- Phase C: row max + argmax (first-max tie-break, numpy semantics)
    float mv[TB]; int mi[TB];
    #pragma unroll
    for (int r = 0; r < TB; ++r) {
        float4 a = acc[r];
        float v = a.x; int i = 4 * t;
        if (a.y > v) { v = a.y; i = 4 * t + 1; }
        if (a.z > v) { v = a.z; i = 4 * t + 2; }
        if (a.w > v) { v = a.w; i = 4 * t + 3; }
        mv[r] = v; mi[r] = i;
    }
    #pragma unroll
    for (int r = 0; r < TB; ++r) {
        #pragma unroll
        for (int off = 32; off >= 1; off >>= 1) {
            float ov = __shfl_xor(mv[r], off, 64);
            int   oi = __shfl_xor(mi[r], off, 64);
            if (ov > mv[r] || (ov == mv[r] && oi < mi[r])) { mv[r] = ov; mi[r] = oi; }
        }
    }
    if (lane == 0) {
        #pragma unroll
        for (int r = 0; r < TB; ++r) { s_maxp[wv][r] = mv[r]; s_argp[wv][r] = mi[r]; }
    }
    __syncthreads();
    if (t < TB) {
        float v = s_maxp[0][t]; int i = s_argp[0][t];
        #pragma unroll
        for (int w = 1; w < 4; ++w) {
            float ov = s_maxp[w][t]; int oi = s_argp[w][t];
            if (ov > v || (ov == v && oi < i)) { v = ov; i = oi; }
        }
        s_rowmax[t] = v; s_rowarg[t] = i;
        argm_out[b0 + t] = (float)i;          // out buffer is read as float32
    }
    __syncthreads();

    // ---- Phase D: exp + row sums
    float sl[TB];
    #pragma unroll
    for (int r = 0; r < TB; ++r) {
        float rm = s_rowmax[r];
        float4 a = acc[r];
        a.x = __expf(ALPHA * (a.x - rm));
        a.y = __expf(ALPHA * (a.y - rm));
        a.z = __expf(ALPHA * (a.z - rm));
        a.w = __expf(ALPHA * (a.w - rm));
        acc[r] = a;
        sl[r] = a.x + a.y + a.z + a.w;
    }
    #pragma unroll
    for (int r = 0; r < TB; ++r) sl[r] = wave_reduce_sum(sl[r]);
    if (lane == 0) {
        #pragma unroll
        for (int r = 0; r < TB; ++r) s_sump[wv][r] = sl[r];
    }
    __syncthreads();
    if (t < TB) {
        float tot = s_sump[0][t] + s_sump[1][t] + s_sump[2][t] + s_sump[3][t];
        s_rowinv[t] = 1.0f / tot;
    }
    __syncthreads();

    // ---- Phase E: write soft_assign (coalesced float4), accumulate avg_probs + cluster metric
    float4 pacc = make_float4(0.f, 0.f, 0.f, 0.f);
    #pragma unroll
    for (int r = 0; r < TB; ++r) {
        float inv = s_rowinv[r];
        float4 sres = make_float4(acc[r].x * inv, acc[r].y * inv, acc[r].z * inv, acc[r].w * inv);
        ((float4*)(soft_out + (size_t)(b0 + r) * KCB))[t] = sres;
        pacc.x += sres.x; pacc.y += sres.y; pacc.z += sres.z; pacc.w += sres.w;
    }
    atomicAdd(avg_ws + 4 * t + 0, pacc.x);
    atomicAdd(avg_ws + 4 * t + 1, pacc.y);
    atomicAdd(avg_ws + 4 * t + 2, pacc.z);
    atomicAdd(avg_ws + 4 * t + 3, pacc.w);
    if (t == 0) {
        float cs = 0.f;
        #pragma unroll
        for (int r = 0; r < TB; ++r) cs += s_rowmax[r];
        atomicAdd(clu_ws, cs);
    }

    // ---- Phase F: hard_quantized = emb[argmax]
    const float4* emb4 = (const float4*)emb;
    for (int idx = t; idx < TB * (D / 4); idx += NT) {
        int r = idx >> 7;       // / (D/4)
        int c = idx & 127;
        int a = s_rowarg[r];
        ((float4*)(hq_out + (size_t)(b0 + r) * D))[c] = emb4[(size_t)a * (D / 4) + c];
    }
}

// ---------------- K3: quantized = soft_assign @ emb_weight, fused SSE((q - ln)^2)
__global__ __launch_bounds__(NT) void k_quant(
    const float* __restrict__ lat, const float* __restrict__ emb,
    const float* __restrict__ soft_in, const float* __restrict__ inv_ws,
    float* __restrict__ q_out, float* __restrict__ sse_ws)
{
    __shared__ float sft[TB][D];            // 32 KB: holds half the K range per pass
    const int t  = threadIdx.x;
    const int b0 = blockIdx.x * TB;
    float2 q[TB];
    #pragma unroll
    for (int r = 0; r < TB; ++r) q[r] = make_float2(0.f, 0.f);
    const float2* emb2 = (const float2*)emb;

    for (int p = 0; p < 2; ++p) {
        const float4* s4 = (const float4*)soft_in;
        for (int idx = t; idx < TB * 128; idx += NT) {
            int r = idx >> 7, c = idx & 127;
            ((float4*)&sft[r][0])[c] = s4[(size_t)(b0 + r) * (KCB / 4) + p * 128 + c];
        }
        __syncthreads();
        const int kbase = p * 512;
        for (int kk = 0; kk < 512; kk += 2) {
            float2 w0 = emb2[(size_t)(kbase + kk)     * (D / 2) + t];   // d = 2t, 2t+1
            float2 w1 = emb2[(size_t)(kbase + kk + 1) * (D / 2) + t];
            #pragma unroll
            for (int r = 0; r < TB; ++r) {
                float2 sv = *(const float2*)&sft[r][kk];
                q[r].x += sv.x * w0.x + sv.y * w1.x;
                q[r].y += sv.x * w0.y + sv.y * w1.y;
            }
        }
        __syncthreads();
    }

    const float2* lat2 = (const float2*)lat;
    float sse = 0.f;
    #pragma unroll
    for (int r = 0; r < TB; ++r) {
        int g = b0 + r;
        float inv = inv_ws[g];
        float2 lv = lat2[(size_t)g * (D / 2) + t];
        float dx = q[r].x - lv.x * inv;
        float dy = q[r].y - lv.y * inv;
        sse += dx * dx + dy * dy;
        ((float2*)(q_out + (size_t)g * D))[t] = q[r];
    }
    sse = wave_reduce_sum(sse);
    __shared__ float part[4];
    const int wv = t >> 6, lane = t & 63;
    if (lane == 0) part[wv] = sse;
    __syncthreads();
    if (t == 0) atomicAdd(sse_ws, part[0] + part[1] + part[2] + part[3]);
}

// ---------------- K4: scalars (vq_loss, entropy, cluster_metric)
__global__ __launch_bounds__(NT) void k_final(
    const float* __restrict__ avg_ws, const float* __restrict__ sse_ws, const float* __restrict__ clu_ws,
    float* __restrict__ out_vq, float* __restrict__ out_ent, float* __restrict__ out_cm,
    float invB, float invBD)
{
    const int t = threadIdx.x;
    float ent = 0.f;
    for (int idx = t; idx < KCB; idx += NT) {
        float pv = avg_ws[idx] * invB;
        ent -= pv * logf(pv + 1e-10f);
    }
    ent = wave_reduce_sum(ent);
    __shared__ float part[4];
    const int wv = t >> 6, lane = t & 63;
    if (lane == 0) part[wv] = ent;
    __syncthreads();
    if (t == 0) {
        *out_ent = part[0] + part[1] + part[2] + part[3];
        *out_vq  = 1.25f * (*sse_ws) * invBD;     // (BETA + 1) * MSE
        *out_cm  = (*clu_ws) * invB;
    }
}

extern "C" void kernel_launch(void* const* d_in, const int* in_sizes, int n_in,
                              void* d_out, int out_size, void* d_ws, size_t ws_size,
                              hipStream_t stream)
{
    const float* lat = (const float*)d_in[0];
    const float* emb = (const float*)d_in[1];
    const int B = in_sizes[0] / D;           // 16384
    float* out = (float*)d_out;

    // output layout: quantized | vq_loss | entropy | argm | hard_quantized | soft_assign | cluster_metric
    const size_t vq_off   = (size_t)B * D;
    const size_t ent_off  = vq_off + 1;
    const size_t argm_off = vq_off + 2;
    const size_t hq_off   = argm_off + (size_t)B;
    const size_t soft_off = hq_off + (size_t)B * D;
    const size_t cm_off   = soft_off + (size_t)B * KCB;

    float* ws     = (float*)d_ws;
    float* cbT    = ws;                          // D*K floats (2 MB)
    float* inv_ws = ws + (size_t)D * KCB;        // B floats
    float* avg_ws = inv_ws + B;                  // K floats
    float* sse_ws = avg_ws + KCB;                // 1
    float* clu_ws = sse_ws + 1;                  // 1

    k_init<<<4, NT, 0, stream>>>(avg_ws, sse_ws, clu_ws);
    k_cbt<<<KCB, NT, 0, stream>>>(emb, cbT);
    k_attn<<<B / TB, NT, 0, stream>>>(lat, emb, cbT, inv_ws, avg_ws, clu_ws,
                                      out + soft_off, out + argm_off, out + hq_off);
    k_quant<<<B / TB, NT, 0, stream>>>(lat, emb, out + soft_off, inv_ws, out, sse_ws);
    k_final<<<1, NT, 0, stream>>>(avg_ws, sse_ws, clu_ws,
                                  out + vq_off, out + ent_off, out + cm_off,
                                  1.0f / (float)B, 1.0f / ((float)B * (float)D));
}